// Round 4
// baseline (122.753 us; speedup 1.0000x reference)
//
#include <hip/hip_runtime.h>
#include <stdint.h>

#define N_SITES 100000
#define NPAD    100032   // N rounded up to multiple of 64
#define CIN 64
#define CMID 384
#define COUT 64
#define SHIFT 16

typedef int   v4i __attribute__((ext_vector_type(4)));
typedef unsigned int v4u __attribute__((ext_vector_type(4)));
typedef float v4f __attribute__((ext_vector_type(4)));

// ---------------------------------------------------------------------------
// pack_weights: w1/w3 -> MFMA fragment order (serves as A-operand: byte(l,b)
// of tile t = W[(l>>4)*16+b][t*16+(l&15)]), wdw -> int32 [9][384],
// b2/s2 packed (b lo16 | s hi16), b1/s1/b3/s3 -> int, zero sentinel row.
// ---------------------------------------------------------------------------
__global__ __launch_bounds__(256) void pack_weights(
    const float* __restrict__ w1, const float* __restrict__ w3,
    const float* __restrict__ b1, const float* __restrict__ s1,
    const float* __restrict__ b2, const float* __restrict__ s2,
    const float* __restrict__ b3, const float* __restrict__ s3,
    const float* __restrict__ wdw,
    int8_t* __restrict__ w1p, int8_t* __restrict__ w3p,
    int* __restrict__ q1, int* __restrict__ q3,
    int* __restrict__ wdw32, int* __restrict__ bs2,
    int8_t* __restrict__ x1s)
{
    int o = blockIdx.x * 256 + threadIdx.x;
    if (o < 24 * 64 * 16) {                       // w1p: [t=24][l=64][b=16]
        int t = o >> 10, l = (o >> 4) & 63, b = o & 15;
        int k = ((l >> 4) << 4) + b;
        int col = t * 16 + (l & 15);
        w1p[o] = (int8_t)__float2int_rn(w1[k * CMID + col]);
    }
    int o3 = o - 24 * 64 * 16;
    if (o3 >= 0 && o3 < 6 * 4 * 64 * 16) {        // w3p: [ks=6][t=4][l=64][b=16]
        int ks = o3 >> 12, t = (o3 >> 10) & 3;
        int l = (o3 >> 4) & 63, b = o3 & 15;
        int k = ks * 64 + ((l >> 4) << 4) + b;
        int col = t * 16 + (l & 15);
        w3p[o3] = (int8_t)__float2int_rn(w3[k * COUT + col]);
    }
    if (o < 9 * CMID)
        wdw32[o] = __float2int_rn(wdw[o]);
    if (o < CMID) {
        q1[o] = __float2int_rn(b1[o]);
        q1[CMID + o] = __float2int_rn(s1[o]);
        int bb = __float2int_rn(b2[o]);            // [-1024,1024] fits i16
        int ss = __float2int_rn(s2[o]);            // [1,64]
        bs2[o] = (bb & 0xFFFF) | (ss << 16);
        x1s[(size_t)N_SITES * CMID + o] = 0;       // zero sentinel row
    }
    if (o < COUT) {
        q3[o] = __float2int_rn(b3[o]);
        q3[COUT + o] = __float2int_rn(s3[o]);
    }
}

// ---------------------------------------------------------------------------
// K1f: fused pack+expand. A = w1^T (w1p), B = feats^T (converted in-register).
// D[ch][site]: lane owns 4 consecutive channels of ONE site -> packed dword
// stores. wave = 16 sites; block = 64 sites.
// ---------------------------------------------------------------------------
__global__ __launch_bounds__(256) void k1f(
    const float* __restrict__ feats, const int8_t* __restrict__ w1p,
    const int* __restrict__ q1, int8_t* __restrict__ x1s)
{
    const int lane = threadIdx.x & 63;
    const int wave = threadIdx.x >> 6;
    const int site = blockIdx.x * 64 + wave * 16 + (lane & 15);
    const int rsite = min(site, N_SITES - 1);
    const bool ok = site < N_SITES;
    const int kbase = (lane >> 4) << 4;            // 0,16,32,48
    const int cbase = (lane >> 4) << 2;            // 0,4,8,12

    // B-fragment: 16 floats of this site -> 16 bytes
    v4i b;
    const float* fp = feats + (size_t)rsite * CIN + kbase;
#pragma unroll
    for (int j = 0; j < 4; ++j) {
        v4f f = *(const v4f*)(fp + 4 * j);
        uint32_t pk = (uint32_t)(__float2int_rn(f[0]) & 255)
                    | ((uint32_t)(__float2int_rn(f[1]) & 255) << 8)
                    | ((uint32_t)(__float2int_rn(f[2]) & 255) << 16)
                    | ((uint32_t)__float2int_rn(f[3]) << 24);
        b[j] = (int)pk;
    }

    const v4i* ap = (const v4i*)w1p + lane;
    int8_t* orow = x1s + (size_t)site * CMID;
#pragma unroll
    for (int t = 0; t < 24; ++t) {
        v4i a = ap[t * 64];
        v4i acc = {0, 0, 0, 0};
        acc = __builtin_amdgcn_mfma_i32_16x16x64_i8(a, b, acc, 0, 0, 0);
        const int co = t * 16 + cbase;             // 4 consecutive channels
        const v4i bi = *(const v4i*)(q1 + co);
        const v4i si = *(const v4i*)(q1 + CMID + co);
        uint32_t wrd = 0;
#pragma unroll
        for (int r = 0; r < 4; ++r) {
            int v = (__mul24(acc[r] + bi[r], si[r]) + (1 << (SHIFT - 1))) >> SHIFT;
            v = max(0, min(127, v));
            wrd |= (uint32_t)v << (8 * r);
        }
        if (ok) *(uint32_t*)(orow + co) = wrd;
    }
}

// ---------------------------------------------------------------------------
// K23: fused depthwise + project. block = 64 sites, 384 threads (6 waves).
// Phase 1: thread = fixed 16-ch chunk (c0 = (tid%24)*16) x 4 sites
//   (slb, +16, +32, +48); weights reused across the 4 sites; __mul24 MACs;
//   quantized bytes -> LDS tile [64][400] (padded pitch: 2-way banks = free).
// Phase 2: waves 0-3: MFMA project from LDS (A = w3p), lane owns 4
//   consecutive couts of one site -> float4 stores.
// ---------------------------------------------------------------------------
__global__ __launch_bounds__(384) void k23(
    const int8_t* __restrict__ x1s, const int* __restrict__ nbr,
    const int* __restrict__ wdw32, const int* __restrict__ bs2,
    const int8_t* __restrict__ w3p, const int* __restrict__ q3,
    float* __restrict__ out)
{
    __shared__ int8_t xt[64][400];                 // 25.6 KB
    const int site0 = blockIdx.x * 64;
    const int tid = threadIdx.x;

    // ---------------- phase 1: depthwise ----------------
    {
        const int c0  = (tid % 24) * 16;
        const int slb = tid / 24;                  // 0..15

        int idx[4][9];
#pragma unroll
        for (int s = 0; s < 4; ++s) {
            const int sc = min(site0 + slb + s * 16, N_SITES - 1);
            const int* nb = nbr + (size_t)sc * 9;
#pragma unroll
            for (int k = 0; k < 9; ++k) idx[s][k] = nb[k];
        }

        int acc[4][16];
#pragma unroll
        for (int s = 0; s < 4; ++s)
#pragma unroll
            for (int j = 0; j < 16; ++j) acc[s][j] = 0;

#pragma unroll
        for (int k = 0; k < 9; ++k) {
            int W[16];
#pragma unroll
            for (int j = 0; j < 4; ++j) {
                v4i w4 = *(const v4i*)(wdw32 + k * CMID + c0 + 4 * j);
#pragma unroll
                for (int b = 0; b < 4; ++b) W[j * 4 + b] = w4[b];
            }
#pragma unroll
            for (int s = 0; s < 4; ++s) {
                const v4u V = *(const v4u*)(x1s + (size_t)idx[s][k] * CMID + c0);
#pragma unroll
                for (int j = 0; j < 4; ++j)
#pragma unroll
                    for (int b = 0; b < 4; ++b) {
                        const int v = (int)((V[j] >> (8 * b)) & 0xff);
                        acc[s][j * 4 + b] += __mul24(v, W[j * 4 + b]);
                    }
            }
        }

        v4i BS[4];
#pragma unroll
        for (int j = 0; j < 4; ++j) BS[j] = *(const v4i*)(bs2 + c0 + 4 * j);

#pragma unroll
        for (int s = 0; s < 4; ++s) {
            v4u ow;
#pragma unroll
            for (int j = 0; j < 4; ++j) {
                uint32_t wrd = 0;
#pragma unroll
                for (int b = 0; b < 4; ++b) {
                    const int bsv = BS[j][b];
                    const int bb = (int)(int16_t)(bsv & 0xFFFF);
                    const int ss = bsv >> 16;
                    int t = (__mul24(acc[s][j * 4 + b] + bb, ss)
                             + (1 << (SHIFT - 1))) >> SHIFT;
                    t = max(0, min(127, t));
                    wrd |= (uint32_t)t << (8 * b);
                }
                ow[j] = wrd;
            }
            *(v4u*)(&xt[slb + s * 16][c0]) = ow;
        }
    }
    __syncthreads();

    // ---------------- phase 2: project (waves 0..3) ----------------
    const int wv = tid >> 6;
    if (wv < 4) {
        const int lane = tid & 63;
        const int sl = wv * 16 + (lane & 15);
        const int site = site0 + sl;
        const int kb = (lane >> 4) << 4;
        const int cb = (lane >> 4) << 2;

        v4i acc3[4] = {{0,0,0,0},{0,0,0,0},{0,0,0,0},{0,0,0,0}};
#pragma unroll
        for (int ks = 0; ks < 6; ++ks) {
            const v4i bfr = *(const v4i*)(&xt[sl][ks * 64 + kb]);
#pragma unroll
            for (int t = 0; t < 4; ++t) {
                const v4i afr = *((const v4i*)w3p + (ks * 4 + t) * 64 + lane);
                acc3[t] = __builtin_amdgcn_mfma_i32_16x16x64_i8(afr, bfr, acc3[t], 0, 0, 0);
            }
        }
        if (site < N_SITES) {
            float* orow = out + (size_t)site * COUT;
#pragma unroll
            for (int t = 0; t < 4; ++t) {
                const int co = t * 16 + cb;        // 4 consecutive couts
                const v4i bo = *(const v4i*)(q3 + co);
                const v4i so = *(const v4i*)(q3 + COUT + co);
                v4f o;
#pragma unroll
                for (int r = 0; r < 4; ++r) {
                    int v = (__mul24(acc3[t][r] + bo[r], so[r])
                             + (1 << (SHIFT - 1))) >> SHIFT;
                    v = max(-128, min(127, v));
                    o[r] = (float)v;
                }
                *(v4f*)(orow + co) = o;
            }
        }
    }
}

extern "C" void kernel_launch(void* const* d_in, const int* in_sizes, int n_in,
                              void* d_out, int out_size, void* d_ws, size_t ws_size,
                              hipStream_t stream) {
    const float* feats = (const float*)d_in[0];
    const float* w1    = (const float*)d_in[1];
    const float* b1    = (const float*)d_in[2];
    const float* s1    = (const float*)d_in[3];
    const float* wdw   = (const float*)d_in[4];
    const float* b2    = (const float*)d_in[5];
    const float* s2    = (const float*)d_in[6];
    const float* w3    = (const float*)d_in[7];
    const float* b3    = (const float*)d_in[8];
    const float* s3    = (const float*)d_in[9];
    const int*   nbr   = (const int*)d_in[10];
    float* out = (float*)d_out;

    int8_t* x1s   = (int8_t*)d_ws;                     // (NPAD)*384 (+sentinel row inside)
    int8_t* w1p   = x1s + (size_t)(NPAD + 64) * CMID;  // 24576
    int8_t* w3p   = w1p + 24 * 64 * 16;                // 24576
    int*    q1    = (int*)(w3p + 6 * 4 * 64 * 16);     // 2*384 ints
    int*    q3    = q1 + 2 * CMID;                     // 2*64 ints
    int*    wdw32 = q3 + 2 * COUT;                     // 9*384 ints
    int*    bs2   = wdw32 + 9 * CMID;                  // 384 ints

    pack_weights<<<192, 256, 0, stream>>>(w1, w3, b1, s1, b2, s2, b3, s3, wdw,
                                          w1p, w3p, q1, q3, wdw32, bs2, x1s);
    k1f<<<NPAD / 64, 256, 0, stream>>>(feats, w1p, q1, x1s);
    k23<<<NPAD / 64, 384, 0, stream>>>(x1s, nbr, wdw32, bs2, w3p, q3, out);
}

// Round 5
// 110.181 us; speedup vs baseline: 1.1141x; 1.1141x over previous
//
#include <hip/hip_runtime.h>
#include <stdint.h>

#define N_SITES 100000
#define NPAD    100032   // N rounded up to multiple of 64
#define CIN 64
#define CMID 384
#define COUT 64
#define SHIFT 16

#define FEAT_BLOCKS 6250   // N_SITES*CIN/4/256

typedef int   v4i __attribute__((ext_vector_type(4)));
typedef unsigned int v4u __attribute__((ext_vector_type(4)));

#if __has_builtin(__builtin_amdgcn_sdot4)
#define HAS_SDOT4 1
#else
#define HAS_SDOT4 0
#endif

// ---------------------------------------------------------------------------
// pack_all: blocks [0,6250): feats f32 -> int8.
// blocks [6250, 6250+192): w1p/w3p MFMA B-fragment order, wdw packed-i8
// (taps0-3, taps4-7) + int32 tap8, q-arrays, sentinel row zero.
// ---------------------------------------------------------------------------
__global__ __launch_bounds__(256) void pack_all(
    const float* __restrict__ feats,
    const float* __restrict__ w1, const float* __restrict__ w3,
    const float* __restrict__ b1, const float* __restrict__ s1,
    const float* __restrict__ b2, const float* __restrict__ s2,
    const float* __restrict__ b3, const float* __restrict__ s3,
    const float* __restrict__ wdw,
    int8_t* __restrict__ feats8,
    int8_t* __restrict__ w1p, int8_t* __restrict__ w3p,
    int* __restrict__ q1, int* __restrict__ q3,
    int* __restrict__ wp03, int* __restrict__ wp47, int* __restrict__ w8,
    int* __restrict__ q2b, int* __restrict__ q2s,
    int8_t* __restrict__ x1s)
{
    if (blockIdx.x < FEAT_BLOCKS) {
        int i = blockIdx.x * 256 + threadIdx.x;        // dword index
        if (i >= N_SITES * CIN / 4) return;
        const float4 v = ((const float4*)feats)[i];
        uint32_t w = (uint32_t)(uint8_t)(int8_t)__float2int_rn(v.x)
                   | ((uint32_t)(uint8_t)(int8_t)__float2int_rn(v.y) << 8)
                   | ((uint32_t)(uint8_t)(int8_t)__float2int_rn(v.z) << 16)
                   | ((uint32_t)(uint8_t)(int8_t)__float2int_rn(v.w) << 24);
        ((uint32_t*)feats8)[i] = w;
        return;
    }
    int o = (blockIdx.x - FEAT_BLOCKS) * 256 + threadIdx.x;
    if (o < 24 * 64 * 16) {                       // w1p: [t=24][l=64][b=16]
        int t = o >> 10, l = (o >> 4) & 63, b = o & 15;
        int k = ((l >> 4) << 4) + b;
        int col = t * 16 + (l & 15);
        w1p[o] = (int8_t)__float2int_rn(w1[k * CMID + col]);
    }
    int o3 = o - 24 * 64 * 16;
    if (o3 >= 0 && o3 < 6 * 4 * 64 * 16) {        // w3p: [ks=6][t=4][l=64][b=16]
        int ks = o3 >> 12, t = (o3 >> 10) & 3;
        int l = (o3 >> 4) & 63, b = o3 & 15;
        int k = ks * 64 + ((l >> 4) << 4) + b;
        int col = t * 16 + (l & 15);
        w3p[o3] = (int8_t)__float2int_rn(w3[k * COUT + col]);
    }
    if (o < CMID) {
        // depthwise weights: taps 0-3 and 4-7 packed as i8 bytes, tap 8 int32
        uint32_t p03 = 0, p47 = 0;
#pragma unroll
        for (int k = 0; k < 4; ++k)
            p03 |= (uint32_t)(uint8_t)(int8_t)__float2int_rn(wdw[k * CMID + o]) << (8 * k);
#pragma unroll
        for (int k = 0; k < 4; ++k)
            p47 |= (uint32_t)(uint8_t)(int8_t)__float2int_rn(wdw[(k + 4) * CMID + o]) << (8 * k);
        wp03[o] = (int)p03;
        wp47[o] = (int)p47;
        w8[o]   = __float2int_rn(wdw[8 * CMID + o]);
        q2b[o]  = __float2int_rn(b2[o]);
        q2s[o]  = __float2int_rn(s2[o]);
        q1[o] = __float2int_rn(b1[o]);
        q1[CMID + o] = __float2int_rn(s1[o]);
        x1s[(size_t)N_SITES * CMID + o] = 0;       // zero sentinel row
    }
    if (o < COUT) {
        q3[o] = __float2int_rn(b3[o]);
        q3[COUT + o] = __float2int_rn(s3[o]);
    }
}

// ---------------------------------------------------------------------------
// K1: 1x1 expand as i8 MFMA (round-3 proven). wave = 16 sites x 384 ch.
// ---------------------------------------------------------------------------
__global__ __launch_bounds__(256) void k1_mfma(
    const int8_t* __restrict__ feats8, const int8_t* __restrict__ w1p,
    const int* __restrict__ q1, int8_t* __restrict__ x1s)
{
    const int lane = threadIdx.x & 63;
    const int wave = threadIdx.x >> 6;
    const int site0 = blockIdx.x * 64 + wave * 16;
    const int row0 = site0 + ((lane >> 4) << 2);
    const v4i a = *(const v4i*)(feats8 + (size_t)(site0 + (lane & 15)) * CIN
                                + ((lane >> 4) << 4));
    const v4i* bp = (const v4i*)w1p + lane;
#pragma unroll
    for (int t = 0; t < 24; ++t) {
        v4i b = bp[t * 64];
        v4i acc = {0, 0, 0, 0};
        acc = __builtin_amdgcn_mfma_i32_16x16x64_i8(a, b, acc, 0, 0, 0);
        const int col = t * 16 + (lane & 15);
        const int bi = q1[col], si = q1[CMID + col];
#pragma unroll
        for (int r = 0; r < 4; ++r) {
            int site = row0 + r;
            if (site < N_SITES) {
                int v = (acc[r] + bi) * si + (1 << (SHIFT - 1));
                v >>= SHIFT;
                v = max(0, min(127, v));
                x1s[(size_t)site * CMID + col] = (int8_t)v;
            }
        }
    }
}

// ---------------------------------------------------------------------------
// K2: 3x3 depthwise. thread = 16 channels of one site (round-3 mapping).
// MACs via v_dot4_i32_i8: activation 4-tap dwords built with __byte_perm,
// weights pre-packed per channel. tap 8 via int32 mad. Exact (i8 ranges).
// ---------------------------------------------------------------------------
__global__ __launch_bounds__(256) void k2_dw(
    const int8_t* __restrict__ x1s, const int* __restrict__ nbr,
    const int* __restrict__ wp03, const int* __restrict__ wp47,
    const int* __restrict__ w8, const int* __restrict__ q2b,
    const int* __restrict__ q2s, int8_t* __restrict__ x2s)
{
    const int g = blockIdx.x * 256 + threadIdx.x;
    const int site = g / 24;
    const int c0 = (g - site * 24) << 4;           // channel base, 0..368

    const int* nb = nbr + (size_t)site * 9;
    int idx[9];
#pragma unroll
    for (int k = 0; k < 9; ++k) idx[k] = nb[k];

    v4u V[9];
#pragma unroll
    for (int k = 0; k < 9; ++k)
        V[k] = *(const v4u*)(x1s + (size_t)idx[k] * CMID + c0);

    v4u outw;
#pragma unroll
    for (int j = 0; j < 4; ++j) {
        const v4i wa  = *(const v4i*)(wp03 + c0 + 4 * j);
        const v4i wb  = *(const v4i*)(wp47 + c0 + 4 * j);
        const v4i w8v = *(const v4i*)(w8   + c0 + 4 * j);
        const v4i bb  = *(const v4i*)(q2b  + c0 + 4 * j);
        const v4i ss  = *(const v4i*)(q2s  + c0 + 4 * j);
        uint32_t wrd = 0;
#pragma unroll
        for (int b = 0; b < 4; ++b) {
            const int v8 = (int)((V[8][j] >> (8 * b)) & 0xff);
            int acc = v8 * w8v[b];
#if HAS_SDOT4
            // gather byte b (channel c0+4j+b) of taps 0-3 / 4-7 into dwords
            const unsigned selA = (unsigned)b | ((unsigned)(4 + b) << 4);
            const unsigned selB = ((unsigned)b << 8) | ((unsigned)(4 + b) << 12);
            unsigned t01 = __byte_perm(V[0][j], V[1][j], selA);
            unsigned t23 = __byte_perm(V[2][j], V[3][j], selB);
            unsigned a03 = __byte_perm(t01, t23, 0x7610);
            unsigned u01 = __byte_perm(V[4][j], V[5][j], selA);
            unsigned u23 = __byte_perm(V[6][j], V[7][j], selB);
            unsigned a47 = __byte_perm(u01, u23, 0x7610);
            acc = __builtin_amdgcn_sdot4((int)a03, wa[b], acc, false);
            acc = __builtin_amdgcn_sdot4((int)a47, wb[b], acc, false);
#else
#pragma unroll
            for (int k = 0; k < 4; ++k) {
                const int v = (int)((V[k][j] >> (8 * b)) & 0xff);
                const int w = ((int)wa[b] << (24 - 8 * k)) >> 24;
                acc += v * w;
            }
#pragma unroll
            for (int k = 0; k < 4; ++k) {
                const int v = (int)((V[k + 4][j] >> (8 * b)) & 0xff);
                const int w = ((int)wb[b] << (24 - 8 * k)) >> 24;
                acc += v * w;
            }
#endif
            int t = (__mul24(acc + bb[b], ss[b]) + (1 << (SHIFT - 1))) >> SHIFT;
            t = max(0, min(127, t));
            wrd |= (uint32_t)t << (8 * b);
        }
        outw[j] = wrd;
    }
    *(v4u*)(x2s + (size_t)site * CMID + c0) = outw;
}

// ---------------------------------------------------------------------------
// K3: 1x1 project as i8 MFMA (round-3 proven).
// ---------------------------------------------------------------------------
__global__ __launch_bounds__(256) void k3_mfma(
    const int8_t* __restrict__ x2s, const int8_t* __restrict__ w3p,
    const int* __restrict__ q3, float* __restrict__ out)
{
    const int lane = threadIdx.x & 63;
    const int wave = threadIdx.x >> 6;
    const int site0 = blockIdx.x * 64 + wave * 16;
    const int row0 = site0 + ((lane >> 4) << 2);
    const int8_t* xbase = x2s + (size_t)(site0 + (lane & 15)) * CMID
                          + ((lane >> 4) << 4);
    v4i acc[4] = {{0,0,0,0},{0,0,0,0},{0,0,0,0},{0,0,0,0}};
#pragma unroll
    for (int ks = 0; ks < 6; ++ks) {
        v4i a = *(const v4i*)(xbase + ks * 64);
#pragma unroll
        for (int t = 0; t < 4; ++t) {
            v4i b = *((const v4i*)w3p + (ks * 4 + t) * 64 + lane);
            acc[t] = __builtin_amdgcn_mfma_i32_16x16x64_i8(a, b, acc[t], 0, 0, 0);
        }
    }
#pragma unroll
    for (int t = 0; t < 4; ++t) {
        const int col = t * 16 + (lane & 15);
        const int bo = q3[col], so = q3[COUT + col];
#pragma unroll
        for (int r = 0; r < 4; ++r) {
            int site = row0 + r;
            if (site < N_SITES) {
                int v = (acc[t][r] + bo) * so + (1 << (SHIFT - 1));
                v >>= SHIFT;
                v = max(-128, min(127, v));
                out[(size_t)site * COUT + col] = (float)v;
            }
        }
    }
}

extern "C" void kernel_launch(void* const* d_in, const int* in_sizes, int n_in,
                              void* d_out, int out_size, void* d_ws, size_t ws_size,
                              hipStream_t stream) {
    const float* feats = (const float*)d_in[0];
    const float* w1    = (const float*)d_in[1];
    const float* b1    = (const float*)d_in[2];
    const float* s1    = (const float*)d_in[3];
    const float* wdw   = (const float*)d_in[4];
    const float* b2    = (const float*)d_in[5];
    const float* s2    = (const float*)d_in[6];
    const float* w3    = (const float*)d_in[7];
    const float* b3    = (const float*)d_in[8];
    const float* s3    = (const float*)d_in[9];
    const int*   nbr   = (const int*)d_in[10];
    float* out = (float*)d_out;

    // ws layout (feats8 aliases x2s: k1 finishes reading before k2 writes)
    int8_t* x1s    = (int8_t*)d_ws;                    // NPAD*384 (sentinel row inside)
    int8_t* x2s    = x1s + (size_t)NPAD * CMID;        // NPAD*384
    int8_t* feats8 = x2s;                              // NPAD*64 (alias)
    int8_t* w1p    = x2s + (size_t)NPAD * CMID;        // 24576
    int8_t* w3p    = w1p + 24 * 64 * 16;               // 24576
    int*    q1     = (int*)(w3p + 6 * 4 * 64 * 16);    // 2*384 ints
    int*    q3     = q1 + 2 * CMID;                    // 2*64 ints
    int*    wp03   = q3 + 2 * COUT;                    // 384 ints
    int*    wp47   = wp03 + CMID;                      // 384 ints
    int*    w8     = wp47 + CMID;                      // 384 ints
    int*    q2b    = w8 + CMID;                        // 384 ints
    int*    q2s    = q2b + CMID;                       // 384 ints

    pack_all<<<FEAT_BLOCKS + 192, 256, 0, stream>>>(
        feats, w1, w3, b1, s1, b2, s2, b3, s3, wdw,
        feats8, w1p, w3p, q1, q3, wp03, wp47, w8, q2b, q2s, x1s);
    k1_mfma<<<NPAD / 64, 256, 0, stream>>>(feats8, w1p, q1, x1s);
    k2_dw<<<N_SITES * 24 / 256, 256, 0, stream>>>(x1s, nbr, wp03, wp47, w8,
                                                  q2b, q2s, x2s);
    k3_mfma<<<NPAD / 64, 256, 0, stream>>>(x2s, w3p, q3, out);
}

// Round 6
// 100.195 us; speedup vs baseline: 1.2251x; 1.0997x over previous
//
#include <hip/hip_runtime.h>
#include <stdint.h>

#define N_SITES 100000
#define NPAD    100032   // N rounded up to multiple of 64
#define CIN 64
#define CMID 384
#define COUT 64
#define SHIFT 16

#define FEAT_BLOCKS 6250   // N_SITES*CIN/4/256

typedef int   v4i __attribute__((ext_vector_type(4)));
typedef unsigned int v4u __attribute__((ext_vector_type(4)));
typedef float v4f __attribute__((ext_vector_type(4)));

// ---------------------------------------------------------------------------
// pack_all: blocks [0,6250): feats f32 -> int8.
// blocks [6250,6250+192): w1p/w3p MFMA fragment order, wdw8 int8 [9][384],
// bs2 packed (b lo16 | s hi16), q1/q3 ints, zero sentinel row.
// ---------------------------------------------------------------------------
__global__ __launch_bounds__(256) void pack_all(
    const float* __restrict__ feats,
    const float* __restrict__ w1, const float* __restrict__ w3,
    const float* __restrict__ b1, const float* __restrict__ s1,
    const float* __restrict__ b2, const float* __restrict__ s2,
    const float* __restrict__ b3, const float* __restrict__ s3,
    const float* __restrict__ wdw,
    int8_t* __restrict__ feats8,
    int8_t* __restrict__ w1p, int8_t* __restrict__ w3p,
    int* __restrict__ q1, int* __restrict__ q3,
    int8_t* __restrict__ wdw8, int* __restrict__ bs2,
    int8_t* __restrict__ x1s)
{
    if (blockIdx.x < FEAT_BLOCKS) {
        int i = blockIdx.x * 256 + threadIdx.x;        // dword index
        if (i >= N_SITES * CIN / 4) return;
        const float4 v = ((const float4*)feats)[i];
        uint32_t w = (uint32_t)(uint8_t)(int8_t)__float2int_rn(v.x)
                   | ((uint32_t)(uint8_t)(int8_t)__float2int_rn(v.y) << 8)
                   | ((uint32_t)(uint8_t)(int8_t)__float2int_rn(v.z) << 16)
                   | ((uint32_t)(uint8_t)(int8_t)__float2int_rn(v.w) << 24);
        ((uint32_t*)feats8)[i] = w;
        return;
    }
    int o = (blockIdx.x - FEAT_BLOCKS) * 256 + threadIdx.x;
    if (o < 24 * 64 * 16) {                       // w1p: [t=24][l=64][b=16]
        int t = o >> 10, l = (o >> 4) & 63, b = o & 15;
        int k = ((l >> 4) << 4) + b;
        int col = t * 16 + (l & 15);
        w1p[o] = (int8_t)__float2int_rn(w1[k * CMID + col]);
    }
    int o3 = o - 24 * 64 * 16;
    if (o3 >= 0 && o3 < 6 * 4 * 64 * 16) {        // w3p: [ks=6][t=4][l=64][b=16]
        int ks = o3 >> 12, t = (o3 >> 10) & 3;
        int l = (o3 >> 4) & 63, b = o3 & 15;
        int k = ks * 64 + ((l >> 4) << 4) + b;
        int col = t * 16 + (l & 15);
        w3p[o3] = (int8_t)__float2int_rn(w3[k * COUT + col]);
    }
    if (o < 9 * CMID)                              // wdw8: [k][c] int8
        wdw8[o] = (int8_t)__float2int_rn(wdw[o]);
    if (o < CMID) {
        q1[o] = __float2int_rn(b1[o]);
        q1[CMID + o] = __float2int_rn(s1[o]);
        int bb = __float2int_rn(b2[o]);            // [-1024,1024] fits i16
        int ss = __float2int_rn(s2[o]);            // [1,64]
        bs2[o] = (bb & 0xFFFF) | (ss << 16);
        x1s[(size_t)N_SITES * CMID + o] = 0;       // zero sentinel row
    }
    if (o < COUT) {
        q3[o] = __float2int_rn(b3[o]);
        q3[COUT + o] = __float2int_rn(s3[o]);
    }
}

// ---------------------------------------------------------------------------
// K1: 1x1 expand, swapped operands: A = w1p (channel-rows), B = feats8 row
// fragment. Lane owns 4 consecutive channels of ONE site -> 24 packed dword
// stores (vs 96 byte stores). Orientation proven absmax-0 in round 4.
// ---------------------------------------------------------------------------
__global__ __launch_bounds__(256) void k1_mfma(
    const int8_t* __restrict__ feats8, const int8_t* __restrict__ w1p,
    const int* __restrict__ q1, int8_t* __restrict__ x1s)
{
    const int lane = threadIdx.x & 63;
    const int wave = threadIdx.x >> 6;
    const int site = blockIdx.x * 64 + wave * 16 + (lane & 15);
    const bool ok = site < N_SITES;
    const int cb = (lane >> 4) << 2;               // channel sub-offset 0,4,8,12

    // B-fragment: 16 bytes of this site's feats8 row, k-window (lane>>4)*16
    const v4i b = *(const v4i*)(feats8 + (size_t)site * CIN + ((lane >> 4) << 4));
    const v4i* ap = (const v4i*)w1p + lane;
    int8_t* orow = x1s + (size_t)site * CMID;
#pragma unroll
    for (int t = 0; t < 24; ++t) {
        v4i a = ap[t * 64];
        v4i acc = {0, 0, 0, 0};
        acc = __builtin_amdgcn_mfma_i32_16x16x64_i8(a, b, acc, 0, 0, 0);
        const int co = t * 16 + cb;                // 4 consecutive channels
        const v4i bi = *(const v4i*)(q1 + co);
        const v4i si = *(const v4i*)(q1 + CMID + co);
        uint32_t wrd = 0;
#pragma unroll
        for (int r = 0; r < 4; ++r) {
            int v = ((acc[r] + bi[r]) * si[r] + (1 << (SHIFT - 1))) >> SHIFT;
            v = max(0, min(127, v));
            wrd |= (uint32_t)v << (8 * r);
        }
        if (ok) *(uint32_t*)(orow + co) = wrd;
    }
}

// ---------------------------------------------------------------------------
// K2: 3x3 depthwise — EXACT round-3 version (proven 43 us). thread = 16
// channels of one site; tap-major MAC loop overlaps with in-flight gathers.
// ---------------------------------------------------------------------------
__global__ __launch_bounds__(256) void k2_dw(
    const int8_t* __restrict__ x1s, const int* __restrict__ nbr,
    const int8_t* __restrict__ wdw8, const int* __restrict__ bs2,
    int8_t* __restrict__ x2s)
{
    const int g = blockIdx.x * 256 + threadIdx.x;
    const int site = g / 24;
    const int c0 = (g - site * 24) << 4;           // channel base, 0..368

    const int* nb = &nbr[site * 9];
    int idx[9];
#pragma unroll
    for (int k = 0; k < 9; ++k) idx[k] = nb[k];

    v4u V[9];
#pragma unroll
    for (int k = 0; k < 9; ++k) {
        const int off = (idx[k] << 8) + (idx[k] << 7) + c0;   // idx*384 + c0
        V[k] = *(const v4u*)(x1s + off);
    }

    int acc[16];
#pragma unroll
    for (int j = 0; j < 16; ++j) acc[j] = 0;

#pragma unroll
    for (int k = 0; k < 9; ++k) {
        const v4u W = *(const v4u*)(wdw8 + k * CMID + c0);
#pragma unroll
        for (int j = 0; j < 4; ++j) {
#pragma unroll
            for (int b = 0; b < 4; ++b) {
                const int v = (int)(uint8_t)(V[k][j] >> (8 * b));  // [0,127]
                const int w = (int)(int8_t)(W[j] >> (8 * b));      // [-128,127]
                acc[j * 4 + b] += v * w;           // v_mad_i32_i24
            }
        }
    }

    const v4i BS0 = *(const v4i*)(bs2 + c0);
    const v4i BS1 = *(const v4i*)(bs2 + c0 + 4);
    const v4i BS2 = *(const v4i*)(bs2 + c0 + 8);
    const v4i BS3 = *(const v4i*)(bs2 + c0 + 12);
    const v4i BS[4] = {BS0, BS1, BS2, BS3};

    v4u outw;
#pragma unroll
    for (int j = 0; j < 4; ++j) {
        uint32_t wrd = 0;
#pragma unroll
        for (int b = 0; b < 4; ++b) {
            const int bsv = BS[j][b];
            const int bb = (bsv << 16) >> 16;      // sext low 16
            const int ss = bsv >> 16;              // sext high 16
            int t = ((acc[j * 4 + b] + bb) * ss + (1 << (SHIFT - 1))) >> SHIFT;
            t = max(0, min(127, t));
            wrd |= (uint32_t)t << (8 * b);
        }
        outw[j] = wrd;
    }
    *(v4u*)(x2s + (site << 8) + (site << 7) + c0) = outw;
}

// ---------------------------------------------------------------------------
// K3: 1x1 project, swapped operands: A = w3p (cout-rows), B = x2 row
// fragment. Lane owns 4 consecutive couts of ONE site -> 4 contiguous
// float4 stores (64 B segments). Orientation proven absmax-0 in round 4.
// ---------------------------------------------------------------------------
__global__ __launch_bounds__(256) void k3_mfma(
    const int8_t* __restrict__ x2s, const int8_t* __restrict__ w3p,
    const int* __restrict__ q3, float* __restrict__ out)
{
    const int lane = threadIdx.x & 63;
    const int wave = threadIdx.x >> 6;
    const int site = blockIdx.x * 64 + wave * 16 + (lane & 15);
    const int cb = (lane >> 4) << 2;               // cout sub-offset 0,4,8,12
    const int8_t* xrow = x2s + (size_t)site * CMID + ((lane >> 4) << 4);

    v4i acc[4] = {{0,0,0,0},{0,0,0,0},{0,0,0,0},{0,0,0,0}};
#pragma unroll
    for (int ks = 0; ks < 6; ++ks) {
        const v4i bfr = *(const v4i*)(xrow + ks * 64);
#pragma unroll
        for (int t = 0; t < 4; ++t) {
            const v4i afr = *((const v4i*)w3p + (ks * 4 + t) * 64 + lane);
            acc[t] = __builtin_amdgcn_mfma_i32_16x16x64_i8(afr, bfr, acc[t], 0, 0, 0);
        }
    }
    if (site < N_SITES) {
        float* orow = out + (size_t)site * COUT;
#pragma unroll
        for (int t = 0; t < 4; ++t) {
            const int co = t * 16 + cb;            // 4 consecutive couts
            const v4i bo = *(const v4i*)(q3 + co);
            const v4i so = *(const v4i*)(q3 + COUT + co);
            v4f o;
#pragma unroll
            for (int r = 0; r < 4; ++r) {
                int v = ((acc[t][r] + bo[r]) * so[r] + (1 << (SHIFT - 1))) >> SHIFT;
                v = max(-128, min(127, v));
                o[r] = (float)v;
            }
            *(v4f*)(orow + co) = o;
        }
    }
}

extern "C" void kernel_launch(void* const* d_in, const int* in_sizes, int n_in,
                              void* d_out, int out_size, void* d_ws, size_t ws_size,
                              hipStream_t stream) {
    const float* feats = (const float*)d_in[0];
    const float* w1    = (const float*)d_in[1];
    const float* b1    = (const float*)d_in[2];
    const float* s1    = (const float*)d_in[3];
    const float* wdw   = (const float*)d_in[4];
    const float* b2    = (const float*)d_in[5];
    const float* s2    = (const float*)d_in[6];
    const float* w3    = (const float*)d_in[7];
    const float* b3    = (const float*)d_in[8];
    const float* s3    = (const float*)d_in[9];
    const int*   nbr   = (const int*)d_in[10];
    float* out = (float*)d_out;

    // ws layout (feats8 aliases x2s: k1 finishes reading before k2 writes)
    int8_t* x1s    = (int8_t*)d_ws;                    // NPAD*384 (sentinel row inside)
    int8_t* x2s    = x1s + (size_t)NPAD * CMID;        // NPAD*384
    int8_t* feats8 = x2s;                              // NPAD*64 (alias)
    int8_t* w1p    = x2s + (size_t)NPAD * CMID;        // 24576
    int8_t* w3p    = w1p + 24 * 64 * 16;               // 24576
    int*    q1     = (int*)(w3p + 6 * 4 * 64 * 16);    // 2*384 ints
    int*    q3     = q1 + 2 * CMID;                    // 2*64 ints
    int8_t* wdw8   = (int8_t*)(q3 + 2 * COUT);         // 9*384 bytes
    int*    bs2    = (int*)(wdw8 + 9 * CMID);          // 384 ints

    pack_all<<<FEAT_BLOCKS + 192, 256, 0, stream>>>(
        feats, w1, w3, b1, s1, b2, s2, b3, s3, wdw,
        feats8, w1p, w3p, q1, q3, wdw8, bs2, x1s);
    k1_mfma<<<NPAD / 64, 256, 0, stream>>>(feats8, w1p, q1, x1s);
    k2_dw<<<N_SITES * 24 / 256, 256, 0, stream>>>(x1s, nbr, wdw8, bs2, x2s);
    k3_mfma<<<NPAD / 64, 256, 0, stream>>>(x2s, w3p, q3, out);
}